// Round 4
// baseline (936.397 us; speedup 1.0000x reference)
//
#include <hip/hip_runtime.h>
#include <hip/hip_bf16.h>
#include <stdint.h>

#define N_TOK 8192
#define H_DIM 1024
#define D_DIM 2048
#define NEXP  8

#define NSLOT      16384          // N_TOK * 2 routed slots
#define SHARED_ROW 16512          // NSLOT + 128 pad rows
#define HID_ROWS   24704          // SHARED_ROW + N_TOK

typedef __attribute__((ext_vector_type(8))) short          bf16x8;
typedef __attribute__((ext_vector_type(4))) float          f32x4;
typedef __attribute__((ext_vector_type(8))) unsigned short u16x8;

__device__ __forceinline__ unsigned short f2bf(float f) {
    union { float f; uint32_t u; } v; v.f = f;
    uint32_t r = v.u + 0x7fff + ((v.u >> 16) & 1);   // RNE
    return (unsigned short)(r >> 16);
}

__device__ __forceinline__ void gll16(const void* g, void* l) {
    __builtin_amdgcn_global_load_lds(
        (const __attribute__((address_space(1))) void*)g,
        (__attribute__((address_space(3))) void*)l, 16, 0, 0);
}

// ---------------- router: one wave per token ----------------
__global__ void k_router(const float* __restrict__ x, const float* __restrict__ gw,
                         int* __restrict__ tok_e, float* __restrict__ tok_w,
                         int* __restrict__ counts) {
    int l = threadIdx.x & 63;
    int n = blockIdx.x * 4 + (threadIdx.x >> 6);
    const float* xr = x + (size_t)n * H_DIM + l * 16;
    float acc[NEXP];
#pragma unroll
    for (int e = 0; e < NEXP; ++e) acc[e] = 0.f;
#pragma unroll
    for (int j = 0; j < 16; ++j) {
        float xv = xr[j];
        const float4* g4 = (const float4*)(gw + (size_t)(l * 16 + j) * NEXP);
        float4 g0 = g4[0], g1 = g4[1];
        acc[0] += xv * g0.x; acc[1] += xv * g0.y; acc[2] += xv * g0.z; acc[3] += xv * g0.w;
        acc[4] += xv * g1.x; acc[5] += xv * g1.y; acc[6] += xv * g1.z; acc[7] += xv * g1.w;
    }
#pragma unroll
    for (int off = 32; off >= 1; off >>= 1) {
#pragma unroll
        for (int e = 0; e < NEXP; ++e) acc[e] += __shfl_xor(acc[e], off);
    }
    if (l == 0) {
        int e0 = 0; float v0 = acc[0];
#pragma unroll
        for (int e = 1; e < NEXP; ++e) if (acc[e] > v0) { v0 = acc[e]; e0 = e; }
        int e1 = -1; float v1 = -1e30f;
#pragma unroll
        for (int e = 0; e < NEXP; ++e) if (e != e0 && acc[e] > v1) { v1 = acc[e]; e1 = e; }
        float t  = expf(v1 - v0);          // p1/p0
        float w1 = t / (1.f + t);
        float w0 = 1.f - w1;
        tok_e[2 * n]     = e0;  tok_e[2 * n + 1] = e1;
        tok_w[2 * n]     = w0;  tok_w[2 * n + 1] = w1;
        atomicAdd(&counts[e0], 1);
        atomicAdd(&counts[e1], 1);
    }
}

__global__ void k_scan(const int* __restrict__ counts, int* __restrict__ offs) {
    if (threadIdx.x == 0) {
        int s = 0;
        for (int e = 0; e < NEXP; ++e) { offs[e] = s; s += counts[e]; }
    }
}

__global__ void k_assign(const int* __restrict__ tok_e, const float* __restrict__ tok_w,
                         const int* __restrict__ offs, int* __restrict__ cursor,
                         int* __restrict__ slot_token, float* __restrict__ slot_weight) {
    int n = blockIdx.x * 256 + threadIdx.x;
#pragma unroll
    for (int k = 0; k < 2; ++k) {
        int e   = tok_e[2 * n + k];
        float w = tok_w[2 * n + k];
        int pos = atomicAdd(&cursor[e], 1);
        int s   = offs[e] + pos;
        slot_token[s]  = n;
        slot_weight[s] = w;
    }
}

// ---------------- f32 -> bf16 convert (x) ----------------
__global__ void k_cvt_x(const float* __restrict__ x, unsigned short* __restrict__ xb) {
    size_t i = ((size_t)blockIdx.x * 256 + threadIdx.x) * 8;
    float4 a = *(const float4*)(x + i);
    float4 b = *(const float4*)(x + i + 4);
    u16x8 o;
    o[0] = f2bf(a.x); o[1] = f2bf(a.y); o[2] = f2bf(a.z); o[3] = f2bf(a.w);
    o[4] = f2bf(b.x); o[5] = f2bf(b.y); o[6] = f2bf(b.z); o[7] = f2bf(b.w);
    *(u16x8*)(xb + i) = o;
}

// ---------------- transpose + convert: src[R][C] f32 -> dst[C][R] bf16 ----------------
// 64x64 tile per block, float4 loads, u16x8 stores
__global__ void k_tconv(const float* __restrict__ src, unsigned short* __restrict__ dst,
                        int R, int C) {
    __shared__ float tb[64][65];
    size_t mb = (size_t)blockIdx.z * (size_t)R * C;
    src += mb; dst += mb;
    int t = threadIdx.x;
    int r0 = blockIdx.y * 64, c0 = blockIdx.x * 64;
    int c4 = t & 15, rr = t >> 4;           // 16 rows per pass
#pragma unroll
    for (int p = 0; p < 4; ++p) {
        int r = p * 16 + rr;
        float4 v = *(const float4*)(src + (size_t)(r0 + r) * C + c0 + c4 * 4);
        tb[r][c4 * 4 + 0] = v.x; tb[r][c4 * 4 + 1] = v.y;
        tb[r][c4 * 4 + 2] = v.z; tb[r][c4 * 4 + 3] = v.w;
    }
    __syncthreads();
    int rbase = (t & 7) * 8;
#pragma unroll
    for (int p = 0; p < 2; ++p) {
        int cc = p * 32 + (t >> 3);
        u16x8 o;
#pragma unroll
        for (int j = 0; j < 8; ++j) o[j] = f2bf(tb[rbase + j][cc]);
        *(u16x8*)(dst + (size_t)(c0 + cc) * R + r0 + rbase) = o;
    }
}

// ---------------- grouped GEMM1: hid = w * (silu(A@Wg) * (A@Wu)), A gathered -------------
// tile 128(M) x 64(N), BK=64, 4 waves (2x2), per-wave 64x32 dual accumulator
// groups 0..7 routed (slot lists, scaled by slot weight), group 8 = shared (weight 1)
__global__ __launch_bounds__(256, 4) void k_gemm1(
    const unsigned short* __restrict__ xb,
    const unsigned short* __restrict__ wg_t, const unsigned short* __restrict__ wu_t,
    const unsigned short* __restrict__ wsg_t, const unsigned short* __restrict__ wsu_t,
    const int* __restrict__ counts, const int* __restrict__ offs,
    const int* __restrict__ slot_token, const float* __restrict__ slot_weight,
    unsigned short* __restrict__ hid) {
    int g = blockIdx.z;
    int n_g, sbase, hbase;
    if (g < NEXP) { n_g = counts[g]; sbase = offs[g]; hbase = sbase; }
    else          { n_g = N_TOK;     sbase = 0;       hbase = SHARED_ROW; }
    int rt = blockIdx.y;
    if (rt * 128 >= n_g) return;
    int dt = blockIdx.x;                     // 0..31 (N-tiles of 64)

    const unsigned short* Bg = (g < NEXP) ? wg_t + (size_t)g * D_DIM * H_DIM : wsg_t;
    const unsigned short* Bu = (g < NEXP) ? wu_t + (size_t)g * D_DIM * H_DIM : wsu_t;

    __shared__ __attribute__((aligned(16))) char smem[32 * 1024];
    __shared__ float sWt[128];
    char* sA  = smem;                        // 16 KB: 128 rows x 128 B
    char* sBg = smem + 16384;                //  8 KB:  64 rows x 128 B
    char* sBu = smem + 24576;                //  8 KB

    int t = threadIdx.x;
    int w = t >> 6, l = t & 63;
    if (t < 128) {
        int r = rt * 128 + t;
        sWt[t] = (g < NEXP) ? ((r < n_g) ? slot_weight[sbase + r] : 0.f) : 1.f;
    }
    int lr8 = l >> 3, lc8 = l & 7;
    int swz = ((lc8 ^ lr8) << 4);            // inverse-swizzled global source byte

    const char* aptr[4]; char* ldsa[4];
#pragma unroll
    for (int c = 0; c < 4; ++c) {            // A: 16 chunks of 1KB, wave w owns w*4+c
        int chunk = w * 4 + c;
        int row = chunk * 8 + lr8;           // 0..127
        int r = rt * 128 + row;
        int tk;
        if (g == NEXP) tk = r;
        else           tk = (r < n_g) ? slot_token[sbase + r] : slot_token[sbase];
        aptr[c] = (const char*)xb + ((size_t)tk * H_DIM) * 2 + swz;
        ldsa[c] = sA + chunk * 1024;
    }
    const char* bgptr[2]; const char* buptr[2]; char* ldsbg[2]; char* ldsbu[2];
#pragma unroll
    for (int c = 0; c < 2; ++c) {            // B: 8 chunks of 1KB each, wave w owns w*2+c
        int chunk = w * 2 + c;
        int row = chunk * 8 + lr8;           // 0..63
        int nn = dt * 64 + row;
        bgptr[c] = (const char*)Bg + ((size_t)nn * H_DIM) * 2 + swz;
        buptr[c] = (const char*)Bu + ((size_t)nn * H_DIM) * 2 + swz;
        ldsbg[c] = sBg + chunk * 1024;
        ldsbu[c] = sBu + chunk * 1024;
    }

    f32x4 accg[4][2], accu[4][2];
#pragma unroll
    for (int m = 0; m < 4; ++m)
#pragma unroll
        for (int n = 0; n < 2; ++n) { accg[m][n] = 0.f; accu[m][n] = 0.f; }

    int wr = w >> 1, wc = w & 1;
    int lr = l & 15, lg = l >> 4;
    int rsw = (lr & 7) << 4;                 // read-side swizzle

    for (int ks = 0; ks < H_DIM / 64; ++ks) {
        int kb = ks * 128;
#pragma unroll
        for (int c = 0; c < 4; ++c) gll16(aptr[c] + kb, ldsa[c]);
#pragma unroll
        for (int c = 0; c < 2; ++c) {
            gll16(bgptr[c] + kb, ldsbg[c]);
            gll16(buptr[c] + kb, ldsbu[c]);
        }
        __syncthreads();
#pragma unroll
        for (int ksub = 0; ksub < 2; ++ksub) {
            int c0 = (ksub * 64 + lg * 16) ^ rsw;
            bf16x8 a[4], bg[2], bu[2];
#pragma unroll
            for (int m = 0; m < 4; ++m)
                a[m] = *(const bf16x8*)(sA + (wr * 64 + m * 16 + lr) * 128 + c0);
#pragma unroll
            for (int n = 0; n < 2; ++n) {
                bg[n] = *(const bf16x8*)(sBg + (wc * 32 + n * 16 + lr) * 128 + c0);
                bu[n] = *(const bf16x8*)(sBu + (wc * 32 + n * 16 + lr) * 128 + c0);
            }
#pragma unroll
            for (int m = 0; m < 4; ++m)
#pragma unroll
                for (int n = 0; n < 2; ++n) {
                    accg[m][n] = __builtin_amdgcn_mfma_f32_16x16x32_bf16(a[m], bg[n], accg[m][n], 0, 0, 0);
                    accu[m][n] = __builtin_amdgcn_mfma_f32_16x16x32_bf16(a[m], bu[n], accu[m][n], 0, 0, 0);
                }
        }
        __syncthreads();
    }

    int cb = dt * 64 + wc * 32;
#pragma unroll
    for (int m = 0; m < 4; ++m)
#pragma unroll
        for (int n = 0; n < 2; ++n)
#pragma unroll
            for (int i = 0; i < 4; ++i) {
                int trow = wr * 64 + m * 16 + lg * 4 + i;   // tile-local row
                int row = rt * 128 + trow;                  // group-local row
                if (row < n_g) {
                    float gv = accg[m][n][i], uv = accu[m][n][i];
                    float hv = (gv / (1.f + __expf(-gv))) * uv * sWt[trow];  // w*silu(g)*u
                    int col = cb + n * 16 + lr;
                    hid[(size_t)(hbase + row) * D_DIM + col] = f2bf(hv);
                }
            }
}

// ---- GEMM2: out = hid @ Wd^T; MODE 0 shared (store), MODE 1 routed (atomic, pre-weighted)
// tile 128(M) x 64(N), BK=64, 4 waves (2x2), per-wave 64x32 single accumulator
template <int MODE>
__global__ __launch_bounds__(256, 4) void k_gemm2(
    const unsigned short* __restrict__ hid,
    const unsigned short* __restrict__ wd_t, const unsigned short* __restrict__ wsd_t,
    const int* __restrict__ counts, const int* __restrict__ offs,
    const int* __restrict__ slot_token, float* __restrict__ out) {
    int n_g, abase;
    const unsigned short* B;
    if (MODE == 0) { n_g = N_TOK; abase = SHARED_ROW; B = wsd_t; }
    else {
        int g = blockIdx.z;
        n_g = counts[g]; abase = offs[g];
        B = wd_t + (size_t)g * H_DIM * D_DIM;
    }
    int rt = blockIdx.y;
    if (rt * 128 >= n_g) return;
    int ct = blockIdx.x;                     // 0..15 (64-col tiles of H)

    __shared__ __attribute__((aligned(16))) char smem[24 * 1024];
    __shared__ int sTok[128];
    char* sA = smem;                         // 16 KB: 128 rows x 128 B
    char* sB = smem + 16384;                 //  8 KB:  64 rows x 128 B

    int t = threadIdx.x, w = t >> 6, l = t & 63;
    if (MODE == 1 && t < 128) {
        int r = rt * 128 + t;
        sTok[t] = (r < n_g) ? slot_token[abase + r] : 0;
    }
    int lr8 = l >> 3, lc8 = l & 7;
    int swz = ((lc8 ^ lr8) << 4);
    const char* aptr[4]; char* ldsa[4];
#pragma unroll
    for (int c = 0; c < 4; ++c) {
        int chunk = w * 4 + c;
        int row = chunk * 8 + lr8;           // 0..127
        aptr[c] = (const char*)hid + ((size_t)(abase + rt * 128 + row) * D_DIM) * 2 + swz;
        ldsa[c] = sA + chunk * 1024;
    }
    const char* bptr[2]; char* ldsb[2];
#pragma unroll
    for (int c = 0; c < 2; ++c) {
        int chunk = w * 2 + c;
        int row = chunk * 8 + lr8;           // 0..63
        bptr[c] = (const char*)B + ((size_t)(ct * 64 + row) * D_DIM) * 2 + swz;
        ldsb[c] = sB + chunk * 1024;
    }
    f32x4 acc[4][2];
#pragma unroll
    for (int m = 0; m < 4; ++m)
#pragma unroll
        for (int n = 0; n < 2; ++n) acc[m][n] = 0.f;

    int wr = w >> 1, wc = w & 1, lr = l & 15, lg = l >> 4;
    int rsw = (lr & 7) << 4;

    for (int ks = 0; ks < D_DIM / 64; ++ks) {
        int kb = ks * 128;
#pragma unroll
        for (int c = 0; c < 4; ++c) gll16(aptr[c] + kb, ldsa[c]);
#pragma unroll
        for (int c = 0; c < 2; ++c) gll16(bptr[c] + kb, ldsb[c]);
        __syncthreads();
#pragma unroll
        for (int ksub = 0; ksub < 2; ++ksub) {
            int c0 = (ksub * 64 + lg * 16) ^ rsw;
            bf16x8 a[4], b[2];
#pragma unroll
            for (int m = 0; m < 4; ++m)
                a[m] = *(const bf16x8*)(sA + (wr * 64 + m * 16 + lr) * 128 + c0);
#pragma unroll
            for (int n = 0; n < 2; ++n)
                b[n] = *(const bf16x8*)(sB + (wc * 32 + n * 16 + lr) * 128 + c0);
#pragma unroll
            for (int m = 0; m < 4; ++m)
#pragma unroll
                for (int n = 0; n < 2; ++n)
                    acc[m][n] = __builtin_amdgcn_mfma_f32_16x16x32_bf16(a[m], b[n], acc[m][n], 0, 0, 0);
        }
        __syncthreads();
    }

    int cb = ct * 64 + wc * 32;
#pragma unroll
    for (int m = 0; m < 4; ++m)
#pragma unroll
        for (int n = 0; n < 2; ++n)
#pragma unroll
            for (int i = 0; i < 4; ++i) {
                int tr = wr * 64 + m * 16 + lg * 4 + i;   // tile-local row
                int col = cb + n * 16 + lr;
                if (MODE == 0) {
                    out[(size_t)(rt * 128 + tr) * H_DIM + col] = acc[m][n][i];
                } else {
                    if (rt * 128 + tr < n_g) {
                        int tok = sTok[tr];
                        unsafeAtomicAdd(&out[(size_t)tok * H_DIM + col], acc[m][n][i]);
                    }
                }
            }
}

// ---------------- launch ----------------
extern "C" void kernel_launch(void* const* d_in, const int* in_sizes, int n_in,
                              void* d_out, int out_size, void* d_ws, size_t ws_size,
                              hipStream_t stream) {
    const float* x       = (const float*)d_in[0];
    const float* gw      = (const float*)d_in[1];
    const float* w_gate  = (const float*)d_in[2];
    const float* w_up    = (const float*)d_in[3];
    const float* w_down  = (const float*)d_in[4];
    const float* ws_gate = (const float*)d_in[5];
    const float* ws_up   = (const float*)d_in[6];
    const float* ws_down = (const float*)d_in[7];
    float* out = (float*)d_out;
    char* ws = (char*)d_ws;

    const size_t oXB    = 0;
    const size_t oWG    = oXB    + (size_t)N_TOK * H_DIM * 2;            // 16 MB
    const size_t oWU    = oWG    + (size_t)NEXP * D_DIM * H_DIM * 2;     // +32 MB
    const size_t oWD    = oWU    + (size_t)NEXP * D_DIM * H_DIM * 2;
    const size_t oWSG   = oWD    + (size_t)NEXP * H_DIM * D_DIM * 2;
    const size_t oWSU   = oWSG   + (size_t)D_DIM * H_DIM * 2;
    const size_t oWSD   = oWSU   + (size_t)D_DIM * H_DIM * 2;
    const size_t oHID   = oWSD   + (size_t)H_DIM * D_DIM * 2;
    const size_t oTOKE  = oHID   + (size_t)HID_ROWS * D_DIM * 2;
    const size_t oTOKW  = oTOKE  + (size_t)N_TOK * 2 * 4;
    const size_t oSLOTT = oTOKW  + (size_t)N_TOK * 2 * 4;
    const size_t oSLOTW = oSLOTT + (size_t)(NSLOT + 128) * 4;
    const size_t oCTRL  = oSLOTW + (size_t)(NSLOT + 128) * 4;

    unsigned short* xb    = (unsigned short*)(ws + oXB);
    unsigned short* wg_t  = (unsigned short*)(ws + oWG);
    unsigned short* wu_t  = (unsigned short*)(ws + oWU);
    unsigned short* wd_t  = (unsigned short*)(ws + oWD);
    unsigned short* wsg_t = (unsigned short*)(ws + oWSG);
    unsigned short* wsu_t = (unsigned short*)(ws + oWSU);
    unsigned short* wsd_t = (unsigned short*)(ws + oWSD);
    unsigned short* hid   = (unsigned short*)(ws + oHID);
    int*   tok_e       = (int*)(ws + oTOKE);
    float* tok_w       = (float*)(ws + oTOKW);
    int*   slot_token  = (int*)(ws + oSLOTT);
    float* slot_weight = (float*)(ws + oSLOTW);
    int*   counts      = (int*)(ws + oCTRL);
    int*   offs        = counts + 8;
    int*   cursor      = counts + 16;

    hipMemsetAsync(counts, 0, 256, stream);
    k_router<<<N_TOK / 4, 256, 0, stream>>>(x, gw, tok_e, tok_w, counts);
    k_scan<<<1, 64, 0, stream>>>(counts, offs);
    k_assign<<<N_TOK / 256, 256, 0, stream>>>(tok_e, tok_w, offs, cursor, slot_token, slot_weight);

    k_cvt_x<<<(N_TOK * H_DIM) / (8 * 256), 256, 0, stream>>>(x, xb);
    k_tconv<<<dim3(D_DIM / 64, H_DIM / 64, NEXP), 256, 0, stream>>>(w_gate, wg_t, H_DIM, D_DIM);
    k_tconv<<<dim3(D_DIM / 64, H_DIM / 64, NEXP), 256, 0, stream>>>(w_up,   wu_t, H_DIM, D_DIM);
    k_tconv<<<dim3(H_DIM / 64, D_DIM / 64, NEXP), 256, 0, stream>>>(w_down, wd_t, D_DIM, H_DIM);
    k_tconv<<<dim3(D_DIM / 64, H_DIM / 64, 1),    256, 0, stream>>>(ws_gate, wsg_t, H_DIM, D_DIM);
    k_tconv<<<dim3(D_DIM / 64, H_DIM / 64, 1),    256, 0, stream>>>(ws_up,   wsu_t, H_DIM, D_DIM);
    k_tconv<<<dim3(H_DIM / 64, D_DIM / 64, 1),    256, 0, stream>>>(ws_down, wsd_t, D_DIM, H_DIM);

    k_gemm1<<<dim3(32, 64, NEXP + 1), 256, 0, stream>>>(xb, wg_t, wu_t, wsg_t, wsu_t,
                                                        counts, offs, slot_token, slot_weight, hid);
    k_gemm2<0><<<dim3(16, 64, 1), 256, 0, stream>>>(hid, wd_t, wsd_t, counts, offs,
                                                    slot_token, out);
    k_gemm2<1><<<dim3(16, 64, NEXP), 256, 0, stream>>>(hid, wd_t, wsd_t, counts, offs,
                                                       slot_token, out);
}

// Round 7
// 759.252 us; speedup vs baseline: 1.2333x; 1.2333x over previous
//
#include <hip/hip_runtime.h>
#include <hip/hip_bf16.h>
#include <stdint.h>

#define N_TOK 8192
#define H_DIM 1024
#define D_DIM 2048
#define NEXP  8

#define NSLOT      16384          // N_TOK * 2 routed slots
#define SHARED_ROW 16512          // NSLOT + 128 pad rows
#define HID_ROWS   24704          // SHARED_ROW + N_TOK

typedef __attribute__((ext_vector_type(8))) short          bf16x8;
typedef __attribute__((ext_vector_type(4))) float          f32x4;
typedef __attribute__((ext_vector_type(8))) unsigned short u16x8;

__device__ __forceinline__ unsigned short f2bf(float f) {
    union { float f; uint32_t u; } v; v.f = f;
    uint32_t r = v.u + 0x7fff + ((v.u >> 16) & 1);   // RNE
    return (unsigned short)(r >> 16);
}

__device__ __forceinline__ void gll16(const void* g, void* l) {
    __builtin_amdgcn_global_load_lds(
        (const __attribute__((address_space(1))) void*)g,
        (__attribute__((address_space(3))) void*)l, 16, 0, 0);
}

// ---------------- router: one wave per token; also emits xb (bf16 x) ----------------
__global__ void k_router(const float* __restrict__ x, const float* __restrict__ gw,
                         int* __restrict__ tok_e, float* __restrict__ tok_w,
                         unsigned short* __restrict__ xb) {
    int l = threadIdx.x & 63;
    int n = blockIdx.x * 4 + (threadIdx.x >> 6);
    const float4* xr4 = (const float4*)(x + (size_t)n * H_DIM + l * 16);
    float4 v0 = xr4[0], v1 = xr4[1], v2 = xr4[2], v3 = xr4[3];
    float xv[16] = {v0.x, v0.y, v0.z, v0.w, v1.x, v1.y, v1.z, v1.w,
                    v2.x, v2.y, v2.z, v2.w, v3.x, v3.y, v3.z, v3.w};
    float acc[NEXP];
#pragma unroll
    for (int e = 0; e < NEXP; ++e) acc[e] = 0.f;
#pragma unroll
    for (int j = 0; j < 16; ++j) {
        float xvj = xv[j];
        const float4* g4 = (const float4*)(gw + (size_t)(l * 16 + j) * NEXP);
        float4 g0 = g4[0], g1 = g4[1];
        acc[0] += xvj * g0.x; acc[1] += xvj * g0.y; acc[2] += xvj * g0.z; acc[3] += xvj * g0.w;
        acc[4] += xvj * g1.x; acc[5] += xvj * g1.y; acc[6] += xvj * g1.z; acc[7] += xvj * g1.w;
    }
    // write bf16 x row (fused cvt)
    u16x8 o0, o1;
#pragma unroll
    for (int j = 0; j < 8; ++j) { o0[j] = f2bf(xv[j]); o1[j] = f2bf(xv[j + 8]); }
    unsigned short* xbr = xb + (size_t)n * H_DIM + l * 16;
    *(u16x8*)(xbr)     = o0;
    *(u16x8*)(xbr + 8) = o1;

#pragma unroll
    for (int off = 32; off >= 1; off >>= 1) {
#pragma unroll
        for (int e = 0; e < NEXP; ++e) acc[e] += __shfl_xor(acc[e], off);
    }
    if (l == 0) {
        int e0 = 0; float v0m = acc[0];
#pragma unroll
        for (int e = 1; e < NEXP; ++e) if (acc[e] > v0m) { v0m = acc[e]; e0 = e; }
        int e1 = -1; float v1m = -1e30f;
#pragma unroll
        for (int e = 0; e < NEXP; ++e) if (e != e0 && acc[e] > v1m) { v1m = acc[e]; e1 = e; }
        float t  = expf(v1m - v0m);        // p1/p0
        float w1 = t / (1.f + t);
        float w0 = 1.f - w1;
        tok_e[2 * n]     = e0;  tok_e[2 * n + 1] = e1;
        tok_w[2 * n]     = w0;  tok_w[2 * n + 1] = w1;
    }
}

// ---------------- dispatch: 1 block, 8 waves; deterministic token-sorted slots ----------
__global__ __launch_bounds__(512) void k_dispatch(
    const int* __restrict__ tok_e, const float* __restrict__ tok_w,
    int* __restrict__ counts, int* __restrict__ offs,
    int* __restrict__ slot_token, float* __restrict__ slot_weight,
    int* __restrict__ slot_of) {
    __shared__ int se[2 * N_TOK];
    __shared__ int scnt[NEXP];
    int t = threadIdx.x, w = t >> 6, l = t & 63;     // wave w = expert w
    for (int i = t; i < 2 * N_TOK; i += 512) se[i] = tok_e[i];
    __syncthreads();
    // count
    int cnt = 0;
    for (int i = l; i < 2 * N_TOK; i += 64) cnt += (se[i] == w) ? 1 : 0;
#pragma unroll
    for (int off = 32; off >= 1; off >>= 1) cnt += __shfl_xor(cnt, off);
    if (l == 0) scnt[w] = cnt;
    __syncthreads();
    if (t < NEXP) {
        int b = 0;
        for (int e = 0; e < t; ++e) b += scnt[e];
        offs[t]   = b;
        counts[t] = scnt[t];
    }
    int run = 0;
    for (int e = 0; e < w; ++e) run += scnt[e];
    // assign in token order
    for (int i0 = 0; i0 < 2 * N_TOK; i0 += 64) {
        int i = i0 + l;
        bool mine = (se[i] == w);
        unsigned long long m = __ballot(mine);
        int pos = __popcll(m & ((1ull << l) - 1ull));
        if (mine) {
            int s = run + pos;
            slot_token[s]  = i >> 1;
            slot_weight[s] = tok_w[i];
            slot_of[i]     = s;
        }
        run += __popcll(m);
    }
}

// ---------------- merged transpose+convert: 27 tensors, src[R][C] f32 -> dst[C][R] bf16 --
__global__ void k_tconv_all(const float* __restrict__ w_gate, const float* __restrict__ w_up,
                            const float* __restrict__ w_down,
                            const float* __restrict__ ws_gate, const float* __restrict__ ws_up,
                            const float* __restrict__ ws_down,
                            unsigned short* __restrict__ wg_t, unsigned short* __restrict__ wu_t,
                            unsigned short* __restrict__ wd_t,
                            unsigned short* __restrict__ wsg_t, unsigned short* __restrict__ wsu_t,
                            unsigned short* __restrict__ wsd_t) {
    __shared__ float tb[64][65];
    int z = blockIdx.y;
    const float* src; unsigned short* dst; int R, C;
    if (z < 8)       { R = H_DIM; C = D_DIM; src = w_gate + (size_t)z * R * C;        dst = wg_t + (size_t)z * R * C; }
    else if (z < 16) { R = H_DIM; C = D_DIM; src = w_up   + (size_t)(z - 8) * R * C;  dst = wu_t + (size_t)(z - 8) * R * C; }
    else if (z < 24) { R = D_DIM; C = H_DIM; src = w_down + (size_t)(z - 16) * R * C; dst = wd_t + (size_t)(z - 16) * R * C; }
    else if (z == 24){ R = H_DIM; C = D_DIM; src = ws_gate; dst = wsg_t; }
    else if (z == 25){ R = H_DIM; C = D_DIM; src = ws_up;   dst = wsu_t; }
    else             { R = D_DIM; C = H_DIM; src = ws_down; dst = wsd_t; }
    int ncx = C >> 6;
    int bx = blockIdx.x;
    int c0 = (bx % ncx) * 64, r0 = (bx / ncx) * 64;

    int t = threadIdx.x;
    int c4 = t & 15, rr = t >> 4;           // 16 rows per pass
#pragma unroll
    for (int p = 0; p < 4; ++p) {
        int r = p * 16 + rr;
        float4 v = *(const float4*)(src + (size_t)(r0 + r) * C + c0 + c4 * 4);
        tb[r][c4 * 4 + 0] = v.x; tb[r][c4 * 4 + 1] = v.y;
        tb[r][c4 * 4 + 2] = v.z; tb[r][c4 * 4 + 3] = v.w;
    }
    __syncthreads();
    int rbase = (t & 7) * 8;
#pragma unroll
    for (int p = 0; p < 2; ++p) {
        int cc = p * 32 + (t >> 3);
        u16x8 o;
#pragma unroll
        for (int j = 0; j < 8; ++j) o[j] = f2bf(tb[rbase + j][cc]);
        *(u16x8*)(dst + (size_t)(c0 + cc) * R + r0 + rbase) = o;
    }
}

// ---------------- grouped GEMM1: hid = w * (silu(A@Wg) * (A@Wu)), A gathered -------------
// tile 128(M) x 64(N), BK=64, 4 waves (2x2), per-wave 64x32 dual accumulator
__global__ __launch_bounds__(256, 4) void k_gemm1(
    const unsigned short* __restrict__ xb,
    const unsigned short* __restrict__ wg_t, const unsigned short* __restrict__ wu_t,
    const unsigned short* __restrict__ wsg_t, const unsigned short* __restrict__ wsu_t,
    const int* __restrict__ counts, const int* __restrict__ offs,
    const int* __restrict__ slot_token, const float* __restrict__ slot_weight,
    unsigned short* __restrict__ hid) {
    int g = blockIdx.z;
    int n_g, sbase, hbase;
    if (g < NEXP) { n_g = counts[g]; sbase = offs[g]; hbase = sbase; }
    else          { n_g = N_TOK;     sbase = 0;       hbase = SHARED_ROW; }
    int rt = blockIdx.y;
    if (rt * 128 >= n_g) return;
    int dt = blockIdx.x;                     // 0..31 (N-tiles of 64)

    const unsigned short* Bg = (g < NEXP) ? wg_t + (size_t)g * D_DIM * H_DIM : wsg_t;
    const unsigned short* Bu = (g < NEXP) ? wu_t + (size_t)g * D_DIM * H_DIM : wsu_t;

    __shared__ __attribute__((aligned(16))) char smem[32 * 1024];
    __shared__ float sWt[128];
    char* sA  = smem;                        // 16 KB: 128 rows x 128 B
    char* sBg = smem + 16384;                //  8 KB:  64 rows x 128 B
    char* sBu = smem + 24576;                //  8 KB

    int t = threadIdx.x;
    int w = t >> 6, l = t & 63;
    if (t < 128) {
        int r = rt * 128 + t;
        sWt[t] = (g < NEXP) ? ((r < n_g) ? slot_weight[sbase + r] : 0.f) : 1.f;
    }
    int lr8 = l >> 3, lc8 = l & 7;
    int swz = ((lc8 ^ lr8) << 4);            // inverse-swizzled global source byte

    const char* aptr[4]; char* ldsa[4];
#pragma unroll
    for (int c = 0; c < 4; ++c) {            // A: 16 chunks of 1KB, wave w owns w*4+c
        int chunk = w * 4 + c;
        int row = chunk * 8 + lr8;           // 0..127
        int r = rt * 128 + row;
        int tk;
        if (g == NEXP) tk = r;
        else           tk = (r < n_g) ? slot_token[sbase + r] : slot_token[sbase];
        aptr[c] = (const char*)xb + ((size_t)tk * H_DIM) * 2 + swz;
        ldsa[c] = sA + chunk * 1024;
    }
    const char* bgptr[2]; const char* buptr[2]; char* ldsbg[2]; char* ldsbu[2];
#pragma unroll
    for (int c = 0; c < 2; ++c) {            // B: 8 chunks of 1KB each, wave w owns w*2+c
        int chunk = w * 2 + c;
        int row = chunk * 8 + lr8;           // 0..63
        int nn = dt * 64 + row;
        bgptr[c] = (const char*)Bg + ((size_t)nn * H_DIM) * 2 + swz;
        buptr[c] = (const char*)Bu + ((size_t)nn * H_DIM) * 2 + swz;
        ldsbg[c] = sBg + chunk * 1024;
        ldsbu[c] = sBu + chunk * 1024;
    }

    f32x4 accg[4][2], accu[4][2];
#pragma unroll
    for (int m = 0; m < 4; ++m)
#pragma unroll
        for (int n = 0; n < 2; ++n) { accg[m][n] = 0.f; accu[m][n] = 0.f; }

    int wr = w >> 1, wc = w & 1;
    int lr = l & 15, lg = l >> 4;
    int rsw = (lr & 7) << 4;                 // read-side swizzle

    for (int ks = 0; ks < H_DIM / 64; ++ks) {
        int kb = ks * 128;
#pragma unroll
        for (int c = 0; c < 4; ++c) gll16(aptr[c] + kb, ldsa[c]);
#pragma unroll
        for (int c = 0; c < 2; ++c) {
            gll16(bgptr[c] + kb, ldsbg[c]);
            gll16(buptr[c] + kb, ldsbu[c]);
        }
        __syncthreads();
#pragma unroll
        for (int ksub = 0; ksub < 2; ++ksub) {
            int c0 = (ksub * 64 + lg * 16) ^ rsw;
            bf16x8 a[4], bg[2], bu[2];
#pragma unroll
            for (int m = 0; m < 4; ++m)
                a[m] = *(const bf16x8*)(sA + (wr * 64 + m * 16 + lr) * 128 + c0);
#pragma unroll
            for (int n = 0; n < 2; ++n) {
                bg[n] = *(const bf16x8*)(sBg + (wc * 32 + n * 16 + lr) * 128 + c0);
                bu[n] = *(const bf16x8*)(sBu + (wc * 32 + n * 16 + lr) * 128 + c0);
            }
#pragma unroll
            for (int m = 0; m < 4; ++m)
#pragma unroll
                for (int n = 0; n < 2; ++n) {
                    accg[m][n] = __builtin_amdgcn_mfma_f32_16x16x32_bf16(a[m], bg[n], accg[m][n], 0, 0, 0);
                    accu[m][n] = __builtin_amdgcn_mfma_f32_16x16x32_bf16(a[m], bu[n], accu[m][n], 0, 0, 0);
                }
        }
        __syncthreads();
    }

    int cb = dt * 64 + wc * 32;
#pragma unroll
    for (int m = 0; m < 4; ++m)
#pragma unroll
        for (int n = 0; n < 2; ++n)
#pragma unroll
            for (int i = 0; i < 4; ++i) {
                int trow = wr * 64 + m * 16 + lg * 4 + i;   // tile-local row
                int row = rt * 128 + trow;                  // group-local row
                if (row < n_g) {
                    float gv = accg[m][n][i], uv = accu[m][n][i];
                    float hv = (gv / (1.f + __expf(-gv))) * uv * sWt[trow];  // w*silu(g)*u
                    int col = cb + n * 16 + lr;
                    hid[(size_t)(hbase + row) * D_DIM + col] = f2bf(hv);
                }
            }
}

// ---- GEMM2: MODE 0 shared -> out (f32 store); MODE 1 routed -> y_slot (f32 store) -------
// tile 128(M) x 64(N), BK=64, 4 waves (2x2), per-wave 64x32 single accumulator
template <int MODE>
__global__ __launch_bounds__(256, 4) void k_gemm2(
    const unsigned short* __restrict__ hid,
    const unsigned short* __restrict__ wd_t, const unsigned short* __restrict__ wsd_t,
    const int* __restrict__ counts, const int* __restrict__ offs,
    float* __restrict__ y_slot, float* __restrict__ out) {
    int n_g, abase;
    const unsigned short* B;
    if (MODE == 0) { n_g = N_TOK; abase = SHARED_ROW; B = wsd_t; }
    else {
        int g = blockIdx.z;
        n_g = counts[g]; abase = offs[g];
        B = wd_t + (size_t)g * H_DIM * D_DIM;
    }
    int rt = blockIdx.y;
    if (rt * 128 >= n_g) return;
    int ct = blockIdx.x;                     // 0..15 (64-col tiles of H)

    __shared__ __attribute__((aligned(16))) char smem[24 * 1024];
    char* sA = smem;                         // 16 KB: 128 rows x 128 B
    char* sB = smem + 16384;                 //  8 KB:  64 rows x 128 B

    int t = threadIdx.x, w = t >> 6, l = t & 63;
    int lr8 = l >> 3, lc8 = l & 7;
    int swz = ((lc8 ^ lr8) << 4);
    const char* aptr[4]; char* ldsa[4];
#pragma unroll
    for (int c = 0; c < 4; ++c) {
        int chunk = w * 4 + c;
        int row = chunk * 8 + lr8;           // 0..127
        aptr[c] = (const char*)hid + ((size_t)(abase + rt * 128 + row) * D_DIM) * 2 + swz;
        ldsa[c] = sA + chunk * 1024;
    }
    const char* bptr[2]; char* ldsb[2];
#pragma unroll
    for (int c = 0; c < 2; ++c) {
        int chunk = w * 2 + c;
        int row = chunk * 8 + lr8;           // 0..63
        bptr[c] = (const char*)B + ((size_t)(ct * 64 + row) * D_DIM) * 2 + swz;
        ldsb[c] = sB + chunk * 1024;
    }
    f32x4 acc[4][2];
#pragma unroll
    for (int m = 0; m < 4; ++m)
#pragma unroll
        for (int n = 0; n < 2; ++n) acc[m][n] = 0.f;

    int wr = w >> 1, wc = w & 1, lr = l & 15, lg = l >> 4;
    int rsw = (lr & 7) << 4;

    for (int ks = 0; ks < D_DIM / 64; ++ks) {
        int kb = ks * 128;
#pragma unroll
        for (int c = 0; c < 4; ++c) gll16(aptr[c] + kb, ldsa[c]);
#pragma unroll
        for (int c = 0; c < 2; ++c) gll16(bptr[c] + kb, ldsb[c]);
        __syncthreads();
#pragma unroll
        for (int ksub = 0; ksub < 2; ++ksub) {
            int c0 = (ksub * 64 + lg * 16) ^ rsw;
            bf16x8 a[4], b[2];
#pragma unroll
            for (int m = 0; m < 4; ++m)
                a[m] = *(const bf16x8*)(sA + (wr * 64 + m * 16 + lr) * 128 + c0);
#pragma unroll
            for (int n = 0; n < 2; ++n)
                b[n] = *(const bf16x8*)(sB + (wc * 32 + n * 16 + lr) * 128 + c0);
#pragma unroll
            for (int m = 0; m < 4; ++m)
#pragma unroll
                for (int n = 0; n < 2; ++n)
                    acc[m][n] = __builtin_amdgcn_mfma_f32_16x16x32_bf16(a[m], b[n], acc[m][n], 0, 0, 0);
        }
        __syncthreads();
    }

    int cb = ct * 64 + wc * 32;
#pragma unroll
    for (int m = 0; m < 4; ++m)
#pragma unroll
        for (int n = 0; n < 2; ++n)
#pragma unroll
            for (int i = 0; i < 4; ++i) {
                int tr = wr * 64 + m * 16 + lg * 4 + i;   // tile-local row
                int col = cb + n * 16 + lr;
                if (MODE == 0) {
                    out[(size_t)(rt * 128 + tr) * H_DIM + col] = acc[m][n][i];
                } else {
                    int row = rt * 128 + tr;              // group-local slot row
                    if (row < n_g)
                        y_slot[(size_t)(abase + row) * H_DIM + col] = acc[m][n][i];
                }
            }
}

// ---------------- combine: out[n] += y_slot[s0(n)] + y_slot[s1(n)] ----------------
__global__ void k_combine(const float* __restrict__ y_slot, const int* __restrict__ slot_of,
                          float* __restrict__ out) {
    int n = blockIdx.x * 2 + (threadIdx.x >> 7);
    int c = (threadIdx.x & 127) * 8;
    int s0 = slot_of[2 * n], s1 = slot_of[2 * n + 1];
    const f32x4* p0 = (const f32x4*)(y_slot + (size_t)s0 * H_DIM + c);
    const f32x4* p1 = (const f32x4*)(y_slot + (size_t)s1 * H_DIM + c);
    f32x4* po = (f32x4*)(out + (size_t)n * H_DIM + c);
    po[0] += p0[0] + p1[0];
    po[1] += p0[1] + p1[1];
}

// ---------------- launch ----------------
extern "C" void kernel_launch(void* const* d_in, const int* in_sizes, int n_in,
                              void* d_out, int out_size, void* d_ws, size_t ws_size,
                              hipStream_t stream) {
    const float* x       = (const float*)d_in[0];
    const float* gw      = (const float*)d_in[1];
    const float* w_gate  = (const float*)d_in[2];
    const float* w_up    = (const float*)d_in[3];
    const float* w_down  = (const float*)d_in[4];
    const float* ws_gate = (const float*)d_in[5];
    const float* ws_up   = (const float*)d_in[6];
    const float* ws_down = (const float*)d_in[7];
    float* out = (float*)d_out;
    char* ws = (char*)d_ws;

    const size_t oXB    = 0;
    const size_t oWG    = oXB    + (size_t)N_TOK * H_DIM * 2;            // 16 MB
    const size_t oWU    = oWG    + (size_t)NEXP * D_DIM * H_DIM * 2;     // +32 MB
    const size_t oWD    = oWU    + (size_t)NEXP * D_DIM * H_DIM * 2;
    const size_t oWSG   = oWD    + (size_t)NEXP * H_DIM * D_DIM * 2;
    const size_t oWSU   = oWSG   + (size_t)D_DIM * H_DIM * 2;
    const size_t oWSD   = oWSU   + (size_t)D_DIM * H_DIM * 2;
    const size_t oHID   = oWSD   + (size_t)H_DIM * D_DIM * 2;
    const size_t oTOKE  = oHID   + (size_t)HID_ROWS * D_DIM * 2;
    const size_t oTOKW  = oTOKE  + (size_t)N_TOK * 2 * 4;
    const size_t oSLOTT = oTOKW  + (size_t)N_TOK * 2 * 4;
    const size_t oSLOTW = oSLOTT + (size_t)(NSLOT + 128) * 4;
    const size_t oSLOTO = oSLOTW + (size_t)(NSLOT + 128) * 4;
    const size_t oCTRL  = oSLOTO + (size_t)N_TOK * 2 * 4;

    unsigned short* xb    = (unsigned short*)(ws + oXB);
    unsigned short* wg_t  = (unsigned short*)(ws + oWG);
    unsigned short* wu_t  = (unsigned short*)(ws + oWU);
    unsigned short* wd_t  = (unsigned short*)(ws + oWD);
    unsigned short* wsg_t = (unsigned short*)(ws + oWSG);
    unsigned short* wsu_t = (unsigned short*)(ws + oWSU);
    unsigned short* wsd_t = (unsigned short*)(ws + oWSD);
    unsigned short* hid   = (unsigned short*)(ws + oHID);
    // y_slot (16384 x 1024 f32 = 64 MB) overlays wg_t+wu_t — dead after k_gemm1
    float* y_slot      = (float*)(ws + oWG);
    int*   tok_e       = (int*)(ws + oTOKE);
    float* tok_w       = (float*)(ws + oTOKW);
    int*   slot_token  = (int*)(ws + oSLOTT);
    float* slot_weight = (float*)(ws + oSLOTW);
    int*   slot_of     = (int*)(ws + oSLOTO);
    int*   counts      = (int*)(ws + oCTRL);
    int*   offs        = counts + 8;

    k_router<<<N_TOK / 4, 256, 0, stream>>>(x, gw, tok_e, tok_w, xb);
    k_dispatch<<<1, 512, 0, stream>>>(tok_e, tok_w, counts, offs,
                                      slot_token, slot_weight, slot_of);
    k_tconv_all<<<dim3(512, 27), 256, 0, stream>>>(w_gate, w_up, w_down,
                                                   ws_gate, ws_up, ws_down,
                                                   wg_t, wu_t, wd_t, wsg_t, wsu_t, wsd_t);
    k_gemm1<<<dim3(32, 64, NEXP + 1), 256, 0, stream>>>(xb, wg_t, wu_t, wsg_t, wsu_t,
                                                        counts, offs, slot_token, slot_weight, hid);
    k_gemm2<1><<<dim3(16, 64, NEXP), 256, 0, stream>>>(hid, wd_t, wsd_t, counts, offs,
                                                       y_slot, out);
    k_gemm2<0><<<dim3(16, 64, 1), 256, 0, stream>>>(hid, wd_t, wsd_t, counts, offs,
                                                    y_slot, out);
    k_combine<<<N_TOK / 2, 256, 0, stream>>>(y_slot, slot_of, out);
}